// Round 1
// baseline (3068.049 us; speedup 1.0000x reference)
//
#include <hip/hip_runtime.h>

#define NN 50000
#define NE 1500000
#define DD 128

// ---------------- GEMM: acc = / += relu(in @ W + b) ----------------
template<int INIT>
__global__ __launch_bounds__(256) void gemm_relu_acc(
    const float* __restrict__ in, const float* __restrict__ W,
    const float* __restrict__ bias, float* __restrict__ acc)
{
    __shared__ float Wl[DD][DD];       // 64 KB, W[k][j]
    __shared__ float inl[64][DD + 4];  // padded to dodge bank conflicts
    __shared__ float bl[DD];

    const int tid = threadIdx.x;

    // stage W (16384 floats) as float4
    const float4* W4 = (const float4*)W;
    float4* Wl4 = (float4*)(&Wl[0][0]);
    #pragma unroll
    for (int i = 0; i < 16; ++i) Wl4[tid + 256 * i] = W4[tid + 256 * i];
    if (tid < DD) bl[tid] = bias[tid];

    const int row0 = blockIdx.x * 64;
    // stage input tile 64 x 128 as float4
    for (int i = tid; i < 64 * 32; i += 256) {
        int r = i >> 5, c = i & 31;
        int gr = row0 + r;
        float4 v = make_float4(0.f, 0.f, 0.f, 0.f);
        if (gr < NN) v = ((const float4*)in)[(size_t)gr * 32 + c];
        *((float4*)&inl[r][c * 4]) = v;
    }
    __syncthreads();

    const int cg = tid & 15;   // cols cg*8 .. cg*8+7
    const int rg = tid >> 4;   // rows rg*4 .. rg*4+3

    float a[4][8];
    #pragma unroll
    for (int r = 0; r < 4; ++r)
        #pragma unroll
        for (int c = 0; c < 8; ++c) a[r][c] = 0.f;

    #pragma unroll 4
    for (int k = 0; k < DD; ++k) {
        float w[8];
        #pragma unroll
        for (int c = 0; c < 8; ++c) w[c] = Wl[k][cg * 8 + c];
        #pragma unroll
        for (int r = 0; r < 4; ++r) {
            float xv = inl[rg * 4 + r][k];
            #pragma unroll
            for (int c = 0; c < 8; ++c) a[r][c] = fmaf(xv, w[c], a[r][c]);
        }
    }

    // epilogue: bias + relu, init or accumulate, float4 stores
    #pragma unroll
    for (int r = 0; r < 4; ++r) {
        int gr = row0 + rg * 4 + r;
        if (gr >= NN) continue;
        float* ap = acc + (size_t)gr * DD + cg * 8;
        float v[8];
        #pragma unroll
        for (int c = 0; c < 8; ++c) {
            float t = a[r][c] + bl[cg * 8 + c];
            v[c] = t > 0.f ? t : 0.f;
        }
        if (INIT) {
            float4 o0 = make_float4(v[0], v[1], v[2], v[3]);
            float4 o1 = make_float4(v[4], v[5], v[6], v[7]);
            ((float4*)ap)[0] = o0;
            ((float4*)ap)[1] = o1;
        } else {
            float4 p0 = ((float4*)ap)[0];
            float4 p1 = ((float4*)ap)[1];
            p0.x += v[0]; p0.y += v[1]; p0.z += v[2]; p0.w += v[3];
            p1.x += v[4]; p1.y += v[5]; p1.z += v[6]; p1.w += v[7];
            ((float4*)ap)[0] = p0;
            ((float4*)ap)[1] = p1;
        }
    }
}

// ---------------- scatter: agg[dst] += h[src] for edges with attr==rel ------
__global__ __launch_bounds__(256) void scatter_rel(
    const float* __restrict__ h, const int* __restrict__ src,
    const int* __restrict__ dst, const int* __restrict__ attr,
    int rel, float* __restrict__ agg)
{
    int e = blockIdx.x * 4 + (threadIdx.x >> 6);
    if (e >= NE) return;
    if (attr[e] != rel) return;
    int lane = threadIdx.x & 63;
    int s = src[e], d = dst[e];
    float2 v = ((const float2*)(h + (size_t)s * DD))[lane];
    float* ap = agg + (size_t)d * DD + lane * 2;
    unsafeAtomicAdd(ap, v.x);
    unsafeAtomicAdd(ap + 1, v.y);
}

// ---------------- residual: xn = xp + relu(acc) ----------------
__global__ __launch_bounds__(256) void residual_add(
    const float* __restrict__ xp, const float* __restrict__ acc,
    float* __restrict__ xn)
{
    int i = blockIdx.x * 256 + threadIdx.x;
    if (i >= NN * DD / 4) return;
    float4 x = ((const float4*)xp)[i];
    float4 a = ((const float4*)acc)[i];
    float4 o;
    o.x = x.x + (a.x > 0.f ? a.x : 0.f);
    o.y = x.y + (a.y > 0.f ? a.y : 0.f);
    o.z = x.z + (a.z > 0.f ? a.z : 0.f);
    o.w = x.w + (a.w > 0.f ? a.w : 0.f);
    ((float4*)xn)[i] = o;
}

extern "C" void kernel_launch(void* const* d_in, const int* in_sizes, int n_in,
                              void* d_out, int out_size, void* d_ws, size_t ws_size,
                              hipStream_t stream) {
    const float* x0   = (const float*)d_in[0];
    const float* Ws_s = (const float*)d_in[1];
    const float* bs_s = (const float*)d_in[2];
    const float* Ws_k = (const float*)d_in[3];
    const float* bs_k = (const float*)d_in[4];
    const int*   src  = (const int*)d_in[5];
    const int*   dst  = src + NE;
    const int*   attr = (const int*)d_in[6];
    float* out = (float*)d_out;

    float* x1  = (float*)d_ws;
    float* agg = x1 + (size_t)NN * DD;
    float* acc = agg + (size_t)NN * DD;
    const size_t fbytes = (size_t)NN * DD * sizeof(float);

    const int gGemm = (NN + 63) / 64;          // 782
    const int gScat = NE / 4;                  // 375000
    const int gRes  = (NN * DD / 4 + 255) / 256; // 6250

    auto Wk = [&](int t, int k) { return Ws_k + ((size_t)t * 3 + k) * DD * DD; };
    auto bk = [&](int t, int k) { return bs_k + ((size_t)t * 3 + k) * DD; };

    // ---------- layer 0 ----------
    gemm_relu_acc<1><<<gGemm, 256, 0, stream>>>(x0, Ws_s, bs_s, acc);
    hipMemsetAsync(agg, 0, fbytes, stream);
    scatter_rel<<<gScat, 256, 0, stream>>>(x0, src, dst, attr, 0, agg);
    gemm_relu_acc<0><<<gGemm, 256, 0, stream>>>(agg, Wk(0, 0), bk(0, 0), acc);
    residual_add<<<gRes, 256, 0, stream>>>(x0, acc, x1);

    // ---------- layer 1 ----------
    gemm_relu_acc<1><<<gGemm, 256, 0, stream>>>(x1, Ws_s + DD * DD, bs_s + DD, acc);
    hipMemsetAsync(agg, 0, fbytes, stream);
    scatter_rel<<<gScat, 256, 0, stream>>>(x1, src, dst, attr, 0, agg);
    gemm_relu_acc<0><<<gGemm, 256, 0, stream>>>(agg, Wk(1, 0), bk(1, 0), acc);
    hipMemsetAsync(agg, 0, fbytes, stream);
    scatter_rel<<<gScat, 256, 0, stream>>>(x0, src, dst, attr, 1, agg);
    gemm_relu_acc<0><<<gGemm, 256, 0, stream>>>(agg, Wk(1, 1), bk(1, 1), acc);
    residual_add<<<gRes, 256, 0, stream>>>(x1, acc, out);   // out = x2

    // ---------- layer 2 ----------
    gemm_relu_acc<1><<<gGemm, 256, 0, stream>>>(out, Ws_s + 2 * DD * DD, bs_s + 2 * DD, acc);
    hipMemsetAsync(agg, 0, fbytes, stream);
    scatter_rel<<<gScat, 256, 0, stream>>>(out, src, dst, attr, 0, agg);
    gemm_relu_acc<0><<<gGemm, 256, 0, stream>>>(agg, Wk(2, 0), bk(2, 0), acc);
    hipMemsetAsync(agg, 0, fbytes, stream);
    scatter_rel<<<gScat, 256, 0, stream>>>(x1, src, dst, attr, 1, agg);
    gemm_relu_acc<0><<<gGemm, 256, 0, stream>>>(agg, Wk(2, 1), bk(2, 1), acc);
    hipMemsetAsync(agg, 0, fbytes, stream);
    scatter_rel<<<gScat, 256, 0, stream>>>(x0, src, dst, attr, 2, agg);
    gemm_relu_acc<0><<<gGemm, 256, 0, stream>>>(agg, Wk(2, 2), bk(2, 2), acc);
    residual_add<<<gRes, 256, 0, stream>>>(out, acc, out);  // x3 in place
}

// Round 2
// 1211.200 us; speedup vs baseline: 2.5331x; 2.5331x over previous
//
#include <hip/hip_runtime.h>

#define NN 50000
#define NE 1500000
#define DD 128
#define NB3 ((3 * NN + 255) / 256)   // blocks for 3N-sized scans = 586

// ---------------- CSR build ----------------
__global__ __launch_bounds__(256) void hist_edges(
    const int* __restrict__ dst, const int* __restrict__ attr, int* __restrict__ cnt)
{
    int e = blockIdx.x * 256 + threadIdx.x;
    if (e >= NE) return;
    atomicAdd(&cnt[attr[e] * NN + dst[e]], 1);
}

__global__ __launch_bounds__(256) void scan_block(
    const int* __restrict__ cnt, int* __restrict__ ptr, int* __restrict__ part)
{
    __shared__ int s[256];
    int i = blockIdx.x * 256 + threadIdx.x;
    int v = (i < 3 * NN) ? cnt[i] : 0;
    s[threadIdx.x] = v;
    __syncthreads();
    #pragma unroll
    for (int off = 1; off < 256; off <<= 1) {
        int t = (threadIdx.x >= off) ? s[threadIdx.x - off] : 0;
        __syncthreads();
        s[threadIdx.x] += t;
        __syncthreads();
    }
    if (i < 3 * NN) ptr[i] = s[threadIdx.x] - v;   // exclusive within block
    if (threadIdx.x == 255) part[blockIdx.x] = s[255];
}

__global__ void scan_partials(int* __restrict__ part, int nb, int* __restrict__ ptr_last)
{
    int lane = threadIdx.x;   // 64 threads, 1 block
    int run = 0;
    for (int base = 0; base < nb; base += 64) {
        int i = base + lane;
        int v = (i < nb) ? part[i] : 0;
        int x = v;
        #pragma unroll
        for (int off = 1; off < 64; off <<= 1) {
            int t = __shfl_up(x, off);
            if (lane >= off) x += t;
        }
        if (i < nb) part[i] = run + x - v;          // exclusive
        run += __shfl(x, 63);
    }
    if (lane == 0) *ptr_last = run;                  // ptr[3N] = NE
}

__global__ __launch_bounds__(256) void scan_add(
    int* __restrict__ ptr, const int* __restrict__ part, int* __restrict__ cursor)
{
    int i = blockIdx.x * 256 + threadIdx.x;
    if (i >= 3 * NN) return;
    int v = ptr[i] + part[blockIdx.x];
    ptr[i] = v;
    cursor[i] = v;
}

__global__ __launch_bounds__(256) void place_edges(
    const int* __restrict__ src, const int* __restrict__ dst, const int* __restrict__ attr,
    int* __restrict__ cursor, int* __restrict__ ssrc)
{
    int e = blockIdx.x * 256 + threadIdx.x;
    if (e >= NE) return;
    int b = attr[e] * NN + dst[e];
    int pos = atomicAdd(&cursor[b], 1);
    ssrc[pos] = src[e];
}

// ---------------- gather: agg[n] = sum_{e in CSR[rel][n]} h[src[e]] ----------
__global__ __launch_bounds__(256) void gather_rel(
    const float* __restrict__ h, const int* __restrict__ ptr,
    const int* __restrict__ ssrc, int rel, float* __restrict__ agg)
{
    int n = blockIdx.x * 2 + (threadIdx.x >> 7);
    if (n >= NN) return;
    int d = threadIdx.x & 127;
    const int* p = ptr + rel * NN + n;
    int s0 = p[0], s1 = p[1];
    float a = 0.f;
    for (int e = s0; e < s1; ++e) {
        int s = ssrc[e];                      // broadcast load
        a += h[(size_t)s * DD + d];           // 512B coalesced per edge
    }
    agg[(size_t)n * DD + d] = a;
}

// ---------------- GEMM: relu(in @ W + b) with epilogue modes ----------------
// MODE 0: acc  = relu(...)
// MODE 1: acc += relu(...)
// MODE 2: xn   = xold + acc + relu(...)   (residual fused; relu(sum)=sum since all terms >=0)
template<int MODE>
__global__ __launch_bounds__(256) void gemm_relu(
    const float* __restrict__ in, const float* __restrict__ W,
    const float* __restrict__ bias, float* __restrict__ acc,
    const float* __restrict__ xold, float* __restrict__ xn)
{
    __shared__ float Wl[DD][DD];
    __shared__ float inl[64][DD + 4];
    __shared__ float bl[DD];

    const int tid = threadIdx.x;

    const float4* W4 = (const float4*)W;
    float4* Wl4 = (float4*)(&Wl[0][0]);
    #pragma unroll
    for (int i = 0; i < 16; ++i) Wl4[tid + 256 * i] = W4[tid + 256 * i];
    if (tid < DD) bl[tid] = bias[tid];

    const int row0 = blockIdx.x * 64;
    for (int i = tid; i < 64 * 32; i += 256) {
        int r = i >> 5, c = i & 31;
        int gr = row0 + r;
        float4 v = make_float4(0.f, 0.f, 0.f, 0.f);
        if (gr < NN) v = ((const float4*)in)[(size_t)gr * 32 + c];
        *((float4*)&inl[r][c * 4]) = v;
    }
    __syncthreads();

    const int cg = tid & 15;
    const int rg = tid >> 4;

    float a[4][8];
    #pragma unroll
    for (int r = 0; r < 4; ++r)
        #pragma unroll
        for (int c = 0; c < 8; ++c) a[r][c] = 0.f;

    #pragma unroll 4
    for (int k = 0; k < DD; ++k) {
        float w[8];
        #pragma unroll
        for (int c = 0; c < 8; ++c) w[c] = Wl[k][cg * 8 + c];
        #pragma unroll
        for (int r = 0; r < 4; ++r) {
            float xv = inl[rg * 4 + r][k];
            #pragma unroll
            for (int c = 0; c < 8; ++c) a[r][c] = fmaf(xv, w[c], a[r][c]);
        }
    }

    #pragma unroll
    for (int r = 0; r < 4; ++r) {
        int gr = row0 + rg * 4 + r;
        if (gr >= NN) continue;
        size_t off = (size_t)gr * DD + cg * 8;
        float v[8];
        #pragma unroll
        for (int c = 0; c < 8; ++c) {
            float t = a[r][c] + bl[cg * 8 + c];
            v[c] = t > 0.f ? t : 0.f;
        }
        if (MODE == 0) {
            ((float4*)(acc + off))[0] = make_float4(v[0], v[1], v[2], v[3]);
            ((float4*)(acc + off))[1] = make_float4(v[4], v[5], v[6], v[7]);
        } else {
            float4 p0 = ((const float4*)(acc + off))[0];
            float4 p1 = ((const float4*)(acc + off))[1];
            p0.x += v[0]; p0.y += v[1]; p0.z += v[2]; p0.w += v[3];
            p1.x += v[4]; p1.y += v[5]; p1.z += v[6]; p1.w += v[7];
            if (MODE == 1) {
                ((float4*)(acc + off))[0] = p0;
                ((float4*)(acc + off))[1] = p1;
            } else {
                float4 x0v = ((const float4*)(xold + off))[0];
                float4 x1v = ((const float4*)(xold + off))[1];
                p0.x += x0v.x; p0.y += x0v.y; p0.z += x0v.z; p0.w += x0v.w;
                p1.x += x1v.x; p1.y += x1v.y; p1.z += x1v.z; p1.w += x1v.w;
                ((float4*)(xn + off))[0] = p0;
                ((float4*)(xn + off))[1] = p1;
            }
        }
    }
}

extern "C" void kernel_launch(void* const* d_in, const int* in_sizes, int n_in,
                              void* d_out, int out_size, void* d_ws, size_t ws_size,
                              hipStream_t stream) {
    const float* x0   = (const float*)d_in[0];
    const float* Ws_s = (const float*)d_in[1];
    const float* bs_s = (const float*)d_in[2];
    const float* Ws_k = (const float*)d_in[3];
    const float* bs_k = (const float*)d_in[4];
    const int*   src  = (const int*)d_in[5];
    const int*   dst  = src + NE;
    const int*   attr = (const int*)d_in[6];
    float* out = (float*)d_out;

    float* x1  = (float*)d_ws;
    float* agg = x1 + (size_t)NN * DD;
    float* acc = agg + (size_t)NN * DD;
    int* cnt    = (int*)(acc + (size_t)NN * DD);
    int* ptr    = cnt + 3 * NN;            // 3N+1 entries
    int* cursor = ptr + 3 * NN + 1;
    int* part   = cursor + 3 * NN;         // NB3 entries (pad 1024)
    int* ssrc   = part + 1024;             // NE entries

    const int gGemm = (NN + 63) / 64;
    const int gEdge = (NE + 255) / 256;
    const int gGath = (NN + 1) / 2;

    auto Wk = [&](int t, int k) { return Ws_k + ((size_t)t * 3 + k) * DD * DD; };
    auto bk = [&](int t, int k) { return bs_k + ((size_t)t * 3 + k) * DD; };

    // ---------- CSR build ----------
    hipMemsetAsync(cnt, 0, 3 * NN * sizeof(int), stream);
    hist_edges<<<gEdge, 256, 0, stream>>>(dst, attr, cnt);
    scan_block<<<NB3, 256, 0, stream>>>(cnt, ptr, part);
    scan_partials<<<1, 64, 0, stream>>>(part, NB3, ptr + 3 * NN);
    scan_add<<<NB3, 256, 0, stream>>>(ptr, part, cursor);
    place_edges<<<gEdge, 256, 0, stream>>>(src, dst, attr, cursor, ssrc);

    // ---------- layer 0 ----------
    gemm_relu<0><<<gGemm, 256, 0, stream>>>(x0, Ws_s, bs_s, acc, nullptr, nullptr);
    gather_rel<<<gGath, 256, 0, stream>>>(x0, ptr, ssrc, 0, agg);
    gemm_relu<2><<<gGemm, 256, 0, stream>>>(agg, Wk(0, 0), bk(0, 0), acc, x0, x1);

    // ---------- layer 1 ----------
    gemm_relu<0><<<gGemm, 256, 0, stream>>>(x1, Ws_s + DD * DD, bs_s + DD, acc, nullptr, nullptr);
    gather_rel<<<gGath, 256, 0, stream>>>(x1, ptr, ssrc, 0, agg);
    gemm_relu<1><<<gGemm, 256, 0, stream>>>(agg, Wk(1, 0), bk(1, 0), acc, nullptr, nullptr);
    gather_rel<<<gGath, 256, 0, stream>>>(x0, ptr, ssrc, 1, agg);
    gemm_relu<2><<<gGemm, 256, 0, stream>>>(agg, Wk(1, 1), bk(1, 1), acc, x1, out);

    // ---------- layer 2 ----------
    gemm_relu<0><<<gGemm, 256, 0, stream>>>(out, Ws_s + 2 * DD * DD, bs_s + 2 * DD, acc, nullptr, nullptr);
    gather_rel<<<gGath, 256, 0, stream>>>(out, ptr, ssrc, 0, agg);
    gemm_relu<1><<<gGemm, 256, 0, stream>>>(agg, Wk(2, 0), bk(2, 0), acc, nullptr, nullptr);
    gather_rel<<<gGath, 256, 0, stream>>>(x1, ptr, ssrc, 1, agg);
    gemm_relu<1><<<gGemm, 256, 0, stream>>>(agg, Wk(2, 1), bk(2, 1), acc, nullptr, nullptr);
    gather_rel<<<gGath, 256, 0, stream>>>(x0, ptr, ssrc, 2, agg);
    gemm_relu<2><<<gGemm, 256, 0, stream>>>(agg, Wk(2, 2), bk(2, 2), acc, out, out);
}

// Round 3
// 613.607 us; speedup vs baseline: 5.0000x; 1.9739x over previous
//
#include <hip/hip_runtime.h>

#define NN 50000
#define NE 1500000
#define DD 128
#define NB3 ((3 * NN + 255) / 256)

typedef __attribute__((ext_vector_type(8))) short short8;
typedef __attribute__((ext_vector_type(4))) float f32x4;

__device__ __forceinline__ ushort f2b(float x) {
    uint u = __float_as_uint(x);
    u += 0x7FFFu + ((u >> 16) & 1u);
    return (ushort)(u >> 16);
}
__device__ __forceinline__ float b2f(ushort b) {
    return __uint_as_float(((uint)b) << 16);
}

// ---------------- CSR build ----------------
__global__ __launch_bounds__(256) void hist_edges(
    const int* __restrict__ dst, const int* __restrict__ attr, int* __restrict__ cnt)
{
    int e = blockIdx.x * 256 + threadIdx.x;
    if (e >= NE) return;
    atomicAdd(&cnt[attr[e] * NN + dst[e]], 1);
}

__global__ __launch_bounds__(256) void scan_block(
    const int* __restrict__ cnt, int* __restrict__ ptr, int* __restrict__ part)
{
    __shared__ int s[256];
    int i = blockIdx.x * 256 + threadIdx.x;
    int v = (i < 3 * NN) ? cnt[i] : 0;
    s[threadIdx.x] = v;
    __syncthreads();
    #pragma unroll
    for (int off = 1; off < 256; off <<= 1) {
        int t = (threadIdx.x >= off) ? s[threadIdx.x - off] : 0;
        __syncthreads();
        s[threadIdx.x] += t;
        __syncthreads();
    }
    if (i < 3 * NN) ptr[i] = s[threadIdx.x] - v;
    if (threadIdx.x == 255) part[blockIdx.x] = s[255];
}

__global__ void scan_partials(int* __restrict__ part, int nb, int* __restrict__ ptr_last)
{
    int lane = threadIdx.x;
    int run = 0;
    for (int base = 0; base < nb; base += 64) {
        int i = base + lane;
        int v = (i < nb) ? part[i] : 0;
        int x = v;
        #pragma unroll
        for (int off = 1; off < 64; off <<= 1) {
            int t = __shfl_up(x, off);
            if (lane >= off) x += t;
        }
        if (i < nb) part[i] = run + x - v;
        run += __shfl(x, 63);
    }
    if (lane == 0) *ptr_last = run;
}

__global__ __launch_bounds__(256) void scan_add(
    int* __restrict__ ptr, const int* __restrict__ part, int* __restrict__ cursor)
{
    int i = blockIdx.x * 256 + threadIdx.x;
    if (i >= 3 * NN) return;
    int v = ptr[i] + part[blockIdx.x];
    ptr[i] = v;
    cursor[i] = v;
}

__global__ __launch_bounds__(256) void place_edges(
    const int* __restrict__ src, const int* __restrict__ dst, const int* __restrict__ attr,
    int* __restrict__ cursor, int* __restrict__ ssrc)
{
    int e = blockIdx.x * 256 + threadIdx.x;
    if (e >= NE) return;
    int b = attr[e] * NN + dst[e];
    int pos = atomicAdd(&cursor[b], 1);
    ssrc[pos] = src[e];
}

// ---------------- weight prep: Wt[m][n][k] = bf16(W[m][k][n]) ----------------
__global__ __launch_bounds__(256) void prep_w(
    const float* __restrict__ Ws_s, const float* __restrict__ Ws_k, ushort* __restrict__ wt)
{
    int i = blockIdx.x * 256 + threadIdx.x;     // one f32x4 each; 9*4096 total
    if (i >= 9 * 4096) return;
    int m = i >> 12;
    int f = (i & 4095) * 4;                     // flat elem in mat
    int k = f >> 7, n = f & 127;
    const int tk[6] = {0, 3, 4, 6, 7, 8};
    const float* W = (m < 3) ? (Ws_s + (size_t)m * 16384)
                             : (Ws_k + (size_t)tk[m - 3] * 16384);
    float4 v = *(const float4*)(W + (size_t)k * DD + n);
    ushort* o = wt + (size_t)m * 16384 + k;     // [n][k] layout
    o[(size_t)(n + 0) * DD] = f2b(v.x);
    o[(size_t)(n + 1) * DD] = f2b(v.y);
    o[(size_t)(n + 2) * DD] = f2b(v.z);
    o[(size_t)(n + 3) * DD] = f2b(v.w);
}

// ---------------- f32 -> bf16 convert ----------------
__global__ __launch_bounds__(256) void to_bf16(
    const float* __restrict__ x, ushort* __restrict__ xb)
{
    int i = blockIdx.x * 256 + threadIdx.x;
    if (i >= NN * DD / 4) return;
    float4 v = ((const float4*)x)[i];
    ushort4 o;
    o.x = f2b(v.x); o.y = f2b(v.y); o.z = f2b(v.z); o.w = f2b(v.w);
    ((ushort4*)xb)[i] = o;
}

// ---------------- gather (bf16 in/out, f32 accum) ----------------
__global__ __launch_bounds__(256) void gather_b(
    const ushort* __restrict__ h, const int* __restrict__ ptr,
    const int* __restrict__ ssrc, int rel, ushort* __restrict__ agg)
{
    int n = blockIdx.x * 4 + (threadIdx.x >> 6);
    if (n >= NN) return;
    int lane = threadIdx.x & 63;
    const int* p = ptr + rel * NN + n;
    int s0 = p[0], s1 = p[1];
    float a0 = 0.f, a1 = 0.f;
    for (int e = s0; e < s1; ++e) {
        int s = ssrc[e];
        uint v = ((const uint*)(h + (size_t)s * DD))[lane];
        a0 += b2f((ushort)(v & 0xFFFFu));
        a1 += b2f((ushort)(v >> 16));
    }
    uint o = (uint)f2b(a0) | ((uint)f2b(a1) << 16);
    ((uint*)(agg + (size_t)n * DD))[lane] = o;
}

// ---------------- fused layer: x_new = x_old + sum_s relu(A_s @ W_s + b_s) ----
// NSRC = t+2 sources (self + t+1 relations). MFMA bf16, f32 accum.
template<int NSRC, int WRITEB>
__global__ __launch_bounds__(256) void layer_mm(
    const ushort* __restrict__ s0, const ushort* __restrict__ s1,
    const ushort* __restrict__ s2, const ushort* __restrict__ s3,
    const ushort* __restrict__ w0, const ushort* __restrict__ w1,
    const ushort* __restrict__ w2, const ushort* __restrict__ w3,
    const float* __restrict__ b0, const float* __restrict__ b1,
    const float* __restrict__ b2, const float* __restrict__ b3,
    const float* __restrict__ xold, float* __restrict__ xnew, ushort* __restrict__ xbnew)
{
    __shared__ ushort Atile[64 * 128];   // XOR-swizzled
    const int tid  = threadIdx.x;
    const int wave = tid >> 6, lane = tid & 63;
    const int row0 = blockIdx.x * 64;

    const ushort* srcs[4] = { s0, s1, s2, s3 };
    const ushort* wts[4]  = { w0, w1, w2, w3 };
    const float*  bss[4]  = { b0, b1, b2, b3 };

    float facc[4][2][4];
    #pragma unroll
    for (int rt = 0; rt < 4; ++rt)
        #pragma unroll
        for (int ct = 0; ct < 2; ++ct)
            #pragma unroll
            for (int q = 0; q < 4; ++q) facc[rt][ct][q] = 0.f;

    #pragma unroll
    for (int sidx = 0; sidx < NSRC; ++sidx) {
        const ushort* S = srcs[sidx];
        const ushort* W = wts[sidx];

        __syncthreads();   // protect Atile from previous iteration's readers
        for (int i = tid; i < 1024; i += 256) {       // 16B chunks of A tile
            int r = i >> 4, c = i & 15;
            int gr = row0 + r;
            uint4 v = make_uint4(0, 0, 0, 0);
            if (gr < NN) v = ((const uint4*)(S + (size_t)gr * DD))[c];
            int byte = (r << 8) + (c << 4);
            byte ^= (r & 7) << 4;
            *((uint4*)((char*)Atile + byte)) = v;
        }
        // B fragments from pre-transposed bf16 Wt[n][k] — contiguous 16B loads
        short8 bfr[2][4];
        #pragma unroll
        for (int ct = 0; ct < 2; ++ct)
            #pragma unroll
            for (int ks = 0; ks < 4; ++ks) {
                int col = (wave << 5) + (ct << 4) + (lane & 15);
                int kb  = (ks << 5) + ((lane >> 4) << 3);
                bfr[ct][ks] = *(const short8*)(W + (size_t)col * DD + kb);
            }
        __syncthreads();

        f32x4 c[4][2];
        #pragma unroll
        for (int rt = 0; rt < 4; ++rt)
            #pragma unroll
            for (int ct = 0; ct < 2; ++ct) c[rt][ct] = (f32x4)(0.f);

        #pragma unroll
        for (int rt = 0; rt < 4; ++rt) {
            int row = (rt << 4) + (lane & 15);
            #pragma unroll
            for (int ks = 0; ks < 4; ++ks) {
                int byte = (row << 8) + (ks << 6) + ((lane >> 4) << 4);
                byte ^= (row & 7) << 4;
                short8 a = *((const short8*)((const char*)Atile + byte));
                c[rt][0] = __builtin_amdgcn_mfma_f32_16x16x32_bf16(a, bfr[0][ks], c[rt][0], 0, 0, 0);
                c[rt][1] = __builtin_amdgcn_mfma_f32_16x16x32_bf16(a, bfr[1][ks], c[rt][1], 0, 0, 0);
            }
        }

        const float* B = bss[sidx];
        #pragma unroll
        for (int ct = 0; ct < 2; ++ct) {
            float bb = B[(wave << 5) + (ct << 4) + (lane & 15)];
            #pragma unroll
            for (int rt = 0; rt < 4; ++rt)
                #pragma unroll
                for (int q = 0; q < 4; ++q) {
                    float v = c[rt][ct][q] + bb;
                    facc[rt][ct][q] += v > 0.f ? v : 0.f;
                }
        }
    }

    // epilogue: residual + stores (f32 + optional bf16 copy)
    #pragma unroll
    for (int rt = 0; rt < 4; ++rt)
        #pragma unroll
        for (int q = 0; q < 4; ++q) {
            int row = row0 + (rt << 4) + ((lane >> 4) << 2) + q;
            if (row >= NN) continue;
            #pragma unroll
            for (int ct = 0; ct < 2; ++ct) {
                int col = (wave << 5) + (ct << 4) + (lane & 15);
                size_t off = (size_t)row * DD + col;
                float v = facc[rt][ct][q] + xold[off];
                xnew[off] = v;
                if (WRITEB) xbnew[off] = f2b(v);
            }
        }
}

extern "C" void kernel_launch(void* const* d_in, const int* in_sizes, int n_in,
                              void* d_out, int out_size, void* d_ws, size_t ws_size,
                              hipStream_t stream) {
    const float* x0   = (const float*)d_in[0];
    const float* Ws_s = (const float*)d_in[1];
    const float* bs_s = (const float*)d_in[2];
    const float* Ws_k = (const float*)d_in[3];
    const float* bs_k = (const float*)d_in[4];
    const int*   src  = (const int*)d_in[5];
    const int*   dst  = src + NE;
    const int*   attr = (const int*)d_in[6];
    float* out = (float*)d_out;

    // workspace carve-up
    float*  x1   = (float*)d_ws;                         // 25.6 MB
    ushort* xb0  = (ushort*)(x1 + (size_t)NN * DD);      // 12.8 MB each
    ushort* xb1  = xb0 + (size_t)NN * DD;
    ushort* xb2  = xb1 + (size_t)NN * DD;
    ushort* agg0 = xb2 + (size_t)NN * DD;
    ushort* agg1 = agg0 + (size_t)NN * DD;
    ushort* agg2 = agg1 + (size_t)NN * DD;
    ushort* wtb  = agg2 + (size_t)NN * DD;               // 9 * 16384 * 2B
    int* cnt    = (int*)(wtb + 9 * 16384);
    int* ptr    = cnt + 3 * NN;
    int* cursor = ptr + 3 * NN + 1;
    int* part   = cursor + 3 * NN;
    int* ssrc   = part + 1024;                           // NE ints

    const int gGemm = (NN + 63) / 64;
    const int gEdge = (NE + 255) / 256;
    const int gGath = (NN + 3) / 4;
    const int gConv = (NN * DD / 4 + 255) / 256;

    auto wt = [&](int m) { return wtb + (size_t)m * 16384; };
    // wt slots: 0..2 = Ws_s[t]; 3=Wk00, 4=Wk10, 5=Wk11, 6=Wk20, 7=Wk21, 8=Wk22
    auto bk = [&](int t, int k) { return bs_k + ((size_t)t * 3 + k) * DD; };

    // ---------- CSR build + weight prep ----------
    hipMemsetAsync(cnt, 0, 3 * NN * sizeof(int), stream);
    hist_edges<<<gEdge, 256, 0, stream>>>(dst, attr, cnt);
    scan_block<<<NB3, 256, 0, stream>>>(cnt, ptr, part);
    scan_partials<<<1, 64, 0, stream>>>(part, NB3, ptr + 3 * NN);
    scan_add<<<NB3, 256, 0, stream>>>(ptr, part, cursor);
    place_edges<<<gEdge, 256, 0, stream>>>(src, dst, attr, cursor, ssrc);
    prep_w<<<144, 256, 0, stream>>>(Ws_s, Ws_k, wtb);
    to_bf16<<<gConv, 256, 0, stream>>>(x0, xb0);

    // ---------- layer 0 ----------
    gather_b<<<gGath, 256, 0, stream>>>(xb0, ptr, ssrc, 0, agg0);
    layer_mm<2, 1><<<gGemm, 256, 0, stream>>>(
        xb0, agg0, nullptr, nullptr,
        wt(0), wt(3), nullptr, nullptr,
        bs_s, bk(0, 0), nullptr, nullptr,
        x0, x1, xb1);

    // ---------- layer 1 ----------
    gather_b<<<gGath, 256, 0, stream>>>(xb1, ptr, ssrc, 0, agg0);
    gather_b<<<gGath, 256, 0, stream>>>(xb0, ptr, ssrc, 1, agg1);
    layer_mm<3, 1><<<gGemm, 256, 0, stream>>>(
        xb1, agg0, agg1, nullptr,
        wt(1), wt(4), wt(5), nullptr,
        bs_s + DD, bk(1, 0), bk(1, 1), nullptr,
        x1, out, xb2);                      // x2 lives in d_out

    // ---------- layer 2 ----------
    gather_b<<<gGath, 256, 0, stream>>>(xb2, ptr, ssrc, 0, agg0);
    gather_b<<<gGath, 256, 0, stream>>>(xb1, ptr, ssrc, 1, agg1);
    gather_b<<<gGath, 256, 0, stream>>>(xb0, ptr, ssrc, 2, agg2);
    layer_mm<4, 0><<<gGemm, 256, 0, stream>>>(
        xb2, agg0, agg1, agg2,
        wt(2), wt(6), wt(7), wt(8),
        bs_s + 2 * DD, bk(2, 0), bk(2, 1), bk(2, 2),
        out, out, nullptr);                 // x3 overwrites x2 in d_out
}